// Round 1
// baseline (1326.007 us; speedup 1.0000x reference)
//
#include <hip/hip_runtime.h>
#include <math.h>

#define NB 64
#define NN 4096
#define NF 256
#define ND 128
#define NK 8
#define NCHUNK 16
#define CHROWS 256   // NN / NCHUNK
#define ROWS 16      // rows per block in ln_project

constexpr float LN_EPS_C   = 1e-5f;
constexpr float EPS_ATTN_C = 1e-8f;
constexpr float INV_SCALE  = 0.08838834764831845f; // 1/sqrt(128)

__device__ __forceinline__ float sigmoidf_(float x) { return 1.f / (1.f + expf(-x)); }

// ---------------------------------------------------------------- slot init
__global__ void init_slots_k(const float* __restrict__ init, float* __restrict__ slots) {
    int i = blockIdx.x * 256 + threadIdx.x;      // 65536 total
    slots[i] = init[i & (NK * ND - 1)];
}

// ------------------------------------------- fused LN(inputs) + x@Wk, x@Wv
// grid: (B*N)/ROWS blocks, 256 threads. Thread=output col; 16 rows per block.
__global__ __launch_bounds__(256) void ln_project(
    const float* __restrict__ inp, const float* __restrict__ Wk,
    const float* __restrict__ Wv, const float* __restrict__ lw,
    const float* __restrict__ lb, float* __restrict__ kout,
    float* __restrict__ vout) {
    __shared__ __align__(16) float xs[ROWS][NF];   // 16 KB
    int t = threadIdx.x;
    size_t rowbase = (size_t)blockIdx.x * ROWS;

    // ---- phase 1: LN stats + normalized store to LDS. 16 threads per row.
    {
        int r = t >> 4;          // 0..15
        int seg = t & 15;        // 16 floats each
        const float4* rowp = (const float4*)(inp + (rowbase + r) * NF);
        float4 xv[4];
        float sum = 0.f, sq = 0.f;
#pragma unroll
        for (int i = 0; i < 4; ++i) {
            xv[i] = rowp[seg * 4 + i];
            sum += xv[i].x + xv[i].y + xv[i].z + xv[i].w;
            sq += xv[i].x * xv[i].x + xv[i].y * xv[i].y + xv[i].z * xv[i].z + xv[i].w * xv[i].w;
        }
#pragma unroll
        for (int m = 8; m >= 1; m >>= 1) {
            sum += __shfl_xor(sum, m, 64);
            sq  += __shfl_xor(sq,  m, 64);
        }
        float mu = sum * (1.f / NF);
        float var = sq * (1.f / NF) - mu * mu;
        float rs = rsqrtf(var + LN_EPS_C);
        const float4* lw4 = (const float4*)lw;
        const float4* lb4 = (const float4*)lb;
        float4* xs4 = (float4*)(&xs[r][0]);
#pragma unroll
        for (int i = 0; i < 4; ++i) {
            float4 w = lw4[seg * 4 + i], bb = lb4[seg * 4 + i], x = xv[i], o;
            o.x = (x.x - mu) * rs * w.x + bb.x;
            o.y = (x.y - mu) * rs * w.y + bb.y;
            o.z = (x.z - mu) * rs * w.z + bb.z;
            o.w = (x.w - mu) * rs * w.w + bb.w;
            xs4[seg * 4 + i] = o;
        }
    }
    __syncthreads();

    // ---- phase 2: GEMM. thread = col (0..127 -> k via Wk, 128..255 -> v via Wv)
    const float* W = (t < ND) ? Wk : Wv;
    int c = t & (ND - 1);
    float acc[ROWS];
#pragma unroll
    for (int r = 0; r < ROWS; ++r) acc[r] = 0.f;

    for (int f4 = 0; f4 < NF / 4; ++f4) {
        float w0 = W[(f4 * 4 + 0) * ND + c];
        float w1 = W[(f4 * 4 + 1) * ND + c];
        float w2 = W[(f4 * 4 + 2) * ND + c];
        float w3 = W[(f4 * 4 + 3) * ND + c];
#pragma unroll
        for (int r = 0; r < ROWS; ++r) {
            float4 x4 = ((const float4*)(&xs[r][0]))[f4];
            acc[r] += x4.x * w0 + x4.y * w1 + x4.z * w2 + x4.w * w3;
        }
    }
    float* outp = (t < ND) ? kout : vout;
#pragma unroll
    for (int r = 0; r < ROWS; ++r) outp[(rowbase + r) * ND + c] = acc[r];
}

// ------------------------------------------------- q = LN(slots) @ Wq
// grid: 512 blocks (b*8+kk), 64 threads
__global__ __launch_bounds__(64) void q_kernel(
    const float* __restrict__ slots, const float* __restrict__ Wq,
    const float* __restrict__ lw, const float* __restrict__ lb,
    float* __restrict__ qout) {
    __shared__ float sln[ND];
    int bk = blockIdx.x;
    int t = threadIdx.x;
    const float* sp = slots + (size_t)bk * ND;
    float s0 = sp[t], s1 = sp[t + 64];
    float sum = s0 + s1, sq = s0 * s0 + s1 * s1;
#pragma unroll
    for (int m = 1; m < 64; m <<= 1) {
        sum += __shfl_xor(sum, m, 64);
        sq  += __shfl_xor(sq,  m, 64);
    }
    float mu = sum * (1.f / ND);
    float var = sq * (1.f / ND) - mu * mu;
    float rs = rsqrtf(var + LN_EPS_C);
    sln[t]      = (s0 - mu) * rs * lw[t]      + lb[t];
    sln[t + 64] = (s1 - mu) * rs * lw[t + 64] + lb[t + 64];
    __syncthreads();
    float q0 = 0.f, q1 = 0.f;
    for (int dd = 0; dd < ND; ++dd) {
        float v = sln[dd];
        q0 += v * Wq[dd * ND + t];
        q1 += v * Wq[dd * ND + 64 + t];
    }
    qout[(size_t)bk * ND + t] = q0;
    qout[(size_t)bk * ND + 64 + t] = q1;
}

// ------------- attention pass: logits -> softmax(K) -> partial U, S per chunk
// grid: (NCHUNK, NB), 256 threads
__global__ __launch_bounds__(256) void attn_kernel(
    const float* __restrict__ kbuf, const float* __restrict__ vbuf,
    const float* __restrict__ qbuf, float* __restrict__ pU,
    float* __restrict__ pS) {
    __shared__ __align__(16) float attn_s[CHROWS * NK];   // 8 KB
    int t = threadIdx.x;
    int chunk = blockIdx.x, b = blockIdx.y;
    int n = chunk * CHROWS + t;

    // ---- phase A: logits + softmax over K for this thread's token
    {
        const float4* k4 = (const float4*)(kbuf + ((size_t)b * NN + n) * ND);
        const float4* q4 = (const float4*)(qbuf + (size_t)b * NK * ND);
        float lg[NK];
#pragma unroll
        for (int kk = 0; kk < NK; ++kk) lg[kk] = 0.f;
        for (int j = 0; j < ND / 4; ++j) {
            float4 kx = k4[j];
#pragma unroll
            for (int kk = 0; kk < NK; ++kk) {
                float4 qv = q4[kk * (ND / 4) + j];
                lg[kk] += kx.x * qv.x + kx.y * qv.y + kx.z * qv.z + kx.w * qv.w;
            }
        }
        float mx = -1e30f;
#pragma unroll
        for (int kk = 0; kk < NK; ++kk) { lg[kk] *= INV_SCALE; mx = fmaxf(mx, lg[kk]); }
        float se = 0.f;
        float e[NK];
#pragma unroll
        for (int kk = 0; kk < NK; ++kk) { e[kk] = expf(lg[kk] - mx); se += e[kk]; }
        float inv = 1.f / se;
#pragma unroll
        for (int kk = 0; kk < NK; ++kk) e[kk] = e[kk] * inv + EPS_ATTN_C;
        ((float4*)attn_s)[t * 2]     = make_float4(e[0], e[1], e[2], e[3]);
        ((float4*)attn_s)[t * 2 + 1] = make_float4(e[4], e[5], e[6], e[7]);
    }
    __syncthreads();

    // ---- phase B: U[kk][d] partial accumulation over this chunk
    {
        int d = t & (ND - 1), kg = t >> 7;   // kg selects kk-half (0..3 / 4..7)
        float4 ua = make_float4(0.f, 0.f, 0.f, 0.f);
        const float* vp = vbuf + ((size_t)b * NN + chunk * CHROWS) * ND + d;
        const float4* a4 = (const float4*)attn_s;
        for (int nn2 = 0; nn2 < CHROWS; ++nn2) {
            float vnd = vp[(size_t)nn2 * ND];
            float4 a = a4[nn2 * 2 + kg];
            ua.x += a.x * vnd; ua.y += a.y * vnd;
            ua.z += a.z * vnd; ua.w += a.w * vnd;
        }
        size_t pb = ((size_t)chunk * NB + b) * (NK * ND);
        pU[pb + (kg * 4 + 0) * ND + d] = ua.x;
        pU[pb + (kg * 4 + 1) * ND + d] = ua.y;
        pU[pb + (kg * 4 + 2) * ND + d] = ua.z;
        pU[pb + (kg * 4 + 3) * ND + d] = ua.w;
    }
    __syncthreads();   // protect attn_s reads before tree-reduce overwrites

    // ---- phase C: S[kk] = sum over chunk rows of attn (tree reduce in LDS)
    float4* as4 = (float4*)attn_s;
    for (int s2 = CHROWS / 2; s2 >= 1; s2 >>= 1) {
        if (t < s2) {
            float4 a0 = as4[t * 2],     b0 = as4[(t + s2) * 2];
            float4 a1 = as4[t * 2 + 1], b1 = as4[(t + s2) * 2 + 1];
            a0.x += b0.x; a0.y += b0.y; a0.z += b0.z; a0.w += b0.w;
            a1.x += b1.x; a1.y += b1.y; a1.z += b1.z; a1.w += b1.w;
            as4[t * 2] = a0; as4[t * 2 + 1] = a1;
        }
        __syncthreads();
    }
    if (t < NK) pS[((size_t)chunk * NB + b) * NK + t] = attn_s[t];
}

// -------- reduce partials, normalize, GRU cell, LN, MLP residual
// grid: 512 blocks (b*8+kk), 128 threads
__global__ __launch_bounds__(128) void finish_kernel(
    const float* __restrict__ pU, const float* __restrict__ pS,
    const float* __restrict__ slots_in, const float* __restrict__ wi,
    const float* __restrict__ wh, const float* __restrict__ bi,
    const float* __restrict__ bh, const float* __restrict__ lnw,
    const float* __restrict__ lnb, const float* __restrict__ w1,
    const float* __restrict__ b1, const float* __restrict__ w2,
    const float* __restrict__ b2, float* __restrict__ slots_out) {
    __shared__ float updL[ND], spL[ND], lnL[ND], hL[2 * ND], red[2], red2[2];
    int bk = blockIdx.x;
    int b = bk >> 3, kk = bk & 7;
    int d = threadIdx.x;

    float U = 0.f, S = 0.f;
    for (int c = 0; c < NCHUNK; ++c) {
        U += pU[((size_t)c * NB + b) * (NK * ND) + kk * ND + d];
        S += pS[((size_t)c * NB + b) * NK + kk];
    }
    float upd = U / S;
    float spd = slots_in[(size_t)bk * ND + d];
    updL[d] = upd;
    spL[d] = spd;
    __syncthreads();

    // GRU gates (torch order r, z, n)
    float gxr = bi[d], gxz = bi[ND + d], gxn = bi[2 * ND + d];
    float ghr = bh[d], ghz = bh[ND + d], ghn = bh[2 * ND + d];
    for (int dd = 0; dd < ND; ++dd) {
        float u = updL[dd], s = spL[dd];
        const float* wip = wi + dd * 3 * ND;
        const float* whp = wh + dd * 3 * ND;
        gxr += u * wip[d];          ghr += s * whp[d];
        gxz += u * wip[ND + d];     ghz += s * whp[ND + d];
        gxn += u * wip[2 * ND + d]; ghn += s * whp[2 * ND + d];
    }
    float r_ = sigmoidf_(gxr + ghr);
    float z_ = sigmoidf_(gxz + ghz);
    float nn_ = tanhf(gxn + r_ * ghn);
    float snew = (1.f - z_) * nn_ + z_ * spd;

    // LayerNorm over D across 128 threads (2 waves)
    int wid = d >> 6;
    float sum = snew, sq = snew * snew;
#pragma unroll
    for (int m = 1; m < 64; m <<= 1) {
        sum += __shfl_xor(sum, m, 64);
        sq  += __shfl_xor(sq,  m, 64);
    }
    if ((d & 63) == 0) { red[wid] = sum; red2[wid] = sq; }
    __syncthreads();
    float tot = red[0] + red[1], totq = red2[0] + red2[1];
    float mu = tot * (1.f / ND);
    float var = totq * (1.f / ND) - mu * mu;
    float rs = rsqrtf(var + LN_EPS_C);
    float lnv = (snew - mu) * rs * lnw[d] + lnb[d];
    lnL[d] = lnv;
    __syncthreads();

    // MLP: h = relu(ln @ w1 + b1), out = snew + h @ w2 + b2
    float h0 = b1[d], h1 = b1[ND + d];
    for (int dd = 0; dd < ND; ++dd) {
        float lv = lnL[dd];
        h0 += lv * w1[dd * 2 * ND + d];
        h1 += lv * w1[dd * 2 * ND + ND + d];
    }
    hL[d] = fmaxf(h0, 0.f);
    hL[ND + d] = fmaxf(h1, 0.f);
    __syncthreads();
    float od = snew + b2[d];
    for (int j = 0; j < 2 * ND; ++j) od += hL[j] * w2[j * ND + d];
    slots_out[(size_t)bk * ND + d] = od;
}

// ---------------------------------------------------------------------------
extern "C" void kernel_launch(void* const* d_in, const int* in_sizes, int n_in,
                              void* d_out, int out_size, void* d_ws, size_t ws_size,
                              hipStream_t stream) {
    const float* inp       = (const float*)d_in[0];
    const float* slot_init = (const float*)d_in[1];
    const float* Wq        = (const float*)d_in[2];
    const float* Wk        = (const float*)d_in[3];
    const float* Wv        = (const float*)d_in[4];
    const float* gru_wi    = (const float*)d_in[5];
    const float* gru_wh    = (const float*)d_in[6];
    const float* gru_bi    = (const float*)d_in[7];
    const float* gru_bh    = (const float*)d_in[8];
    const float* ln_in_w   = (const float*)d_in[9];
    const float* ln_in_b   = (const float*)d_in[10];
    const float* ln_sl_w   = (const float*)d_in[11];
    const float* ln_sl_b   = (const float*)d_in[12];
    const float* ln_ml_w   = (const float*)d_in[13];
    const float* ln_ml_b   = (const float*)d_in[14];
    const float* mlp_w1    = (const float*)d_in[15];
    const float* mlp_b1    = (const float*)d_in[16];
    const float* mlp_w2    = (const float*)d_in[17];
    const float* mlp_b2    = (const float*)d_in[18];

    float* ws = (float*)d_ws;
    float* kb = ws;                                   // 33,554,432 floats
    float* vb = kb + (size_t)NB * NN * ND;            // 33,554,432
    float* qb = vb + (size_t)NB * NN * ND;            // 65,536
    float* sl = qb + (size_t)NB * NK * ND;            // 65,536
    float* pU = sl + (size_t)NB * NK * ND;            // 1,048,576
    float* pS = pU + (size_t)NCHUNK * NB * NK * ND;   // 8,192

    init_slots_k<<<(NB * NK * ND) / 256, 256, 0, stream>>>(slot_init, sl);
    ln_project<<<(NB * NN) / ROWS, 256, 0, stream>>>(inp, Wk, Wv, ln_in_w, ln_in_b, kb, vb);

    for (int it = 0; it < 3; ++it) {
        q_kernel<<<NB * NK, 64, 0, stream>>>(sl, Wq, ln_sl_w, ln_sl_b, qb);
        attn_kernel<<<dim3(NCHUNK, NB), 256, 0, stream>>>(kb, vb, qb, pU, pS);
        float* outp = (it == 2) ? (float*)d_out : sl;
        finish_kernel<<<NB * NK, 128, 0, stream>>>(pU, pS, sl, gru_wi, gru_wh,
                                                   gru_bi, gru_bh, ln_ml_w, ln_ml_b,
                                                   mlp_w1, mlp_b1, mlp_w2, mlp_b2, outp);
    }
}

// Round 2
// 702.419 us; speedup vs baseline: 1.8878x; 1.8878x over previous
//
#include <hip/hip_runtime.h>
#include <math.h>

#define NB 64
#define NN 4096
#define NF 256
#define ND 128
#define NK 8
#define NCHUNK 16
#define CHROWS 256   // NN / NCHUNK
#define MT 64        // rows per block in ln_project_mfma

typedef unsigned int uint;
typedef unsigned short ushort;
typedef __attribute__((ext_vector_type(8))) short short8;
typedef __attribute__((ext_vector_type(4))) float floatx4;

constexpr float LN_EPS_C   = 1e-5f;
constexpr float EPS_ATTN_C = 1e-8f;
constexpr float INV_SCALE  = 0.08838834764831845f; // 1/sqrt(128)

__device__ __forceinline__ float sigmoidf_(float x) { return 1.f / (1.f + expf(-x)); }
__device__ __forceinline__ ushort f2bf(float x) {
    uint u = __float_as_uint(x);
    return (ushort)((u + 0x7FFFu + ((u >> 16) & 1u)) >> 16);
}
__device__ __forceinline__ float bflo(uint u) { return __uint_as_float(u << 16); }
__device__ __forceinline__ float bfhi(uint u) { return __uint_as_float(u & 0xFFFF0000u); }

// ---------------------------------------------------------------- slot init
__global__ void init_slots_k(const float* __restrict__ init, float* __restrict__ slots) {
    int i = blockIdx.x * 256 + threadIdx.x;      // 65536 total
    slots[i] = init[i & (NK * ND - 1)];
}

// ------------------------- weight convert: wt[c][f] = bf16(Wkv[f][c]) (transposed)
__global__ void wconv_k(const float* __restrict__ Wk, const float* __restrict__ Wv,
                        ushort* __restrict__ wt) {
    int c = blockIdx.x;      // 0..255
    int f = threadIdx.x;     // 0..255
    float v = (c < ND) ? Wk[(size_t)f * ND + c] : Wv[(size_t)f * ND + (c - ND)];
    wt[(size_t)c * NF + f] = f2bf(v);
}

// -------------------- fused LN(inputs) + [x@Wk, x@Wv] via bf16 MFMA, bf16 out
// grid: (B*N)/MT = 4096 blocks, 256 threads (4 waves)
__global__ __launch_bounds__(256) void ln_project_mfma(
    const float* __restrict__ inp, const ushort* __restrict__ wt,
    const float* __restrict__ lw, const float* __restrict__ lb,
    ushort* __restrict__ kout, ushort* __restrict__ vout) {
    __shared__ ushort As[MT][264];   // padded: 264*2=528 B stride -> conflict-free frags
    int t = threadIdx.x;
    size_t rowbase = (size_t)blockIdx.x * MT;

    // ---- LN phase: 16 threads/row, 16 rows/pass, 4 passes; write bf16 to LDS
    {
        int rloc = t >> 4, seg = t & 15;
        const float4* lw4 = (const float4*)lw;
        const float4* lb4 = (const float4*)lb;
#pragma unroll
        for (int p = 0; p < 4; ++p) {
            int r = p * 16 + rloc;
            const float4* rowp = (const float4*)(inp + (rowbase + r) * NF);
            float4 xv[4];
            float sum = 0.f, sq = 0.f;
#pragma unroll
            for (int i = 0; i < 4; ++i) {
                xv[i] = rowp[seg * 4 + i];
                sum += xv[i].x + xv[i].y + xv[i].z + xv[i].w;
                sq += xv[i].x * xv[i].x + xv[i].y * xv[i].y + xv[i].z * xv[i].z + xv[i].w * xv[i].w;
            }
#pragma unroll
            for (int m = 8; m >= 1; m >>= 1) {
                sum += __shfl_xor(sum, m, 64);
                sq  += __shfl_xor(sq,  m, 64);
            }
            float mu = sum * (1.f / NF);
            float var = sq * (1.f / NF) - mu * mu;
            float rs = rsqrtf(var + LN_EPS_C);
#pragma unroll
            for (int i = 0; i < 4; ++i) {
                float4 w = lw4[seg * 4 + i], bb = lb4[seg * 4 + i], x = xv[i];
                float o0 = (x.x - mu) * rs * w.x + bb.x;
                float o1 = (x.y - mu) * rs * w.y + bb.y;
                float o2 = (x.z - mu) * rs * w.z + bb.z;
                float o3 = (x.w - mu) * rs * w.w + bb.w;
                uint2 pk;
                pk.x = (uint)f2bf(o0) | ((uint)f2bf(o1) << 16);
                pk.y = (uint)f2bf(o2) | ((uint)f2bf(o3) << 16);
                *(uint2*)&As[r][seg * 16 + i * 4] = pk;
            }
        }
    }
    __syncthreads();

    // ---- MFMA phase: wave w covers output cols [w*64, w*64+64)
    int w = t >> 6, lane = t & 63;
    int frow = lane & 15, q = lane >> 4;
    floatx4 acc[4][4];
#pragma unroll
    for (int mt = 0; mt < 4; ++mt)
#pragma unroll
        for (int nt = 0; nt < 4; ++nt) acc[mt][nt] = (floatx4)0.f;

#pragma unroll
    for (int ks = 0; ks < 8; ++ks) {
        short8 a[4], b[4];
#pragma unroll
        for (int mt = 0; mt < 4; ++mt)
            a[mt] = *(const short8*)&As[mt * 16 + frow][ks * 32 + q * 8];
#pragma unroll
        for (int nt = 0; nt < 4; ++nt) {
            int n = w * 64 + nt * 16 + frow;
            b[nt] = *(const short8*)(wt + (size_t)n * NF + ks * 32 + q * 8);
        }
#pragma unroll
        for (int mt = 0; mt < 4; ++mt)
#pragma unroll
            for (int nt = 0; nt < 4; ++nt)
                acc[mt][nt] = __builtin_amdgcn_mfma_f32_16x16x32_bf16(a[mt], b[nt], acc[mt][nt], 0, 0, 0);
    }

    // ---- epilogue: C/D layout col=lane&15, row=(lane>>4)*4+reg
    ushort* outp = (w < 2) ? kout : vout;
    int cbase = (w & 1) * 64;
#pragma unroll
    for (int mt = 0; mt < 4; ++mt)
#pragma unroll
        for (int nt = 0; nt < 4; ++nt) {
            int c = cbase + nt * 16 + frow;
#pragma unroll
            for (int i = 0; i < 4; ++i) {
                int m = mt * 16 + q * 4 + i;
                outp[(rowbase + m) * ND + c] = f2bf(acc[mt][nt][i]);
            }
        }
}

// ------------------------------------------------- q = LN(slots) @ Wq (iter 0 only)
// grid: 512 blocks (b*8+kk), 64 threads
__global__ __launch_bounds__(64) void q_kernel(
    const float* __restrict__ slots, const float* __restrict__ Wq,
    const float* __restrict__ lw, const float* __restrict__ lb,
    float* __restrict__ qout) {
    __shared__ float sln[ND];
    int bk = blockIdx.x;
    int t = threadIdx.x;
    const float* sp = slots + (size_t)bk * ND;
    float s0 = sp[t], s1 = sp[t + 64];
    float sum = s0 + s1, sq = s0 * s0 + s1 * s1;
#pragma unroll
    for (int m = 1; m < 64; m <<= 1) {
        sum += __shfl_xor(sum, m, 64);
        sq  += __shfl_xor(sq,  m, 64);
    }
    float mu = sum * (1.f / ND);
    float var = sq * (1.f / ND) - mu * mu;
    float rs = rsqrtf(var + LN_EPS_C);
    sln[t]      = (s0 - mu) * rs * lw[t]      + lb[t];
    sln[t + 64] = (s1 - mu) * rs * lw[t + 64] + lb[t + 64];
    __syncthreads();
    float q0 = 0.f, q1 = 0.f;
    for (int dd = 0; dd < ND; ++dd) {
        float v = sln[dd];
        q0 += v * Wq[dd * ND + t];
        q1 += v * Wq[dd * ND + 64 + t];
    }
    qout[(size_t)bk * ND + t] = q0;
    qout[(size_t)bk * ND + 64 + t] = q1;
}

// ------------- attention pass: logits -> softmax(K) -> partial U, S per chunk
// grid: (NCHUNK, NB), 256 threads. k/v are bf16.
__global__ __launch_bounds__(256) void attn_kernel(
    const ushort* __restrict__ kbuf, const ushort* __restrict__ vbuf,
    const float* __restrict__ qbuf, float* __restrict__ pU,
    float* __restrict__ pS) {
    __shared__ __align__(16) float attn_s[CHROWS * NK];   // 8 KB
    __shared__ __align__(16) float qs[NK * ND];           // 4 KB
    int t = threadIdx.x;
    int chunk = blockIdx.x, b = blockIdx.y;
    int n = chunk * CHROWS + t;

    ((float4*)qs)[t] = ((const float4*)(qbuf + (size_t)b * NK * ND))[t];
    __syncthreads();

    // ---- phase A: logits + softmax over K for this thread's token
    {
        const uint4* k16 = (const uint4*)(kbuf + ((size_t)b * NN + n) * ND);
        float lg[NK];
#pragma unroll
        for (int kk = 0; kk < NK; ++kk) lg[kk] = 0.f;
        for (int j = 0; j < 16; ++j) {
            uint4 kr = k16[j];
            float k0 = bflo(kr.x), k1 = bfhi(kr.x);
            float k2 = bflo(kr.y), k3 = bfhi(kr.y);
            float k4 = bflo(kr.z), k5 = bfhi(kr.z);
            float k6 = bflo(kr.w), k7 = bfhi(kr.w);
#pragma unroll
            for (int kk = 0; kk < NK; ++kk) {
                const float4* qp = (const float4*)(qs + kk * ND + j * 8);
                float4 q0 = qp[0], q1 = qp[1];
                lg[kk] += k0 * q0.x + k1 * q0.y + k2 * q0.z + k3 * q0.w
                        + k4 * q1.x + k5 * q1.y + k6 * q1.z + k7 * q1.w;
            }
        }
        float mx = -1e30f;
#pragma unroll
        for (int kk = 0; kk < NK; ++kk) { lg[kk] *= INV_SCALE; mx = fmaxf(mx, lg[kk]); }
        float se = 0.f;
        float e[NK];
#pragma unroll
        for (int kk = 0; kk < NK; ++kk) { e[kk] = expf(lg[kk] - mx); se += e[kk]; }
        float inv = 1.f / se;
#pragma unroll
        for (int kk = 0; kk < NK; ++kk) e[kk] = e[kk] * inv + EPS_ATTN_C;
        ((float4*)attn_s)[t * 2]     = make_float4(e[0], e[1], e[2], e[3]);
        ((float4*)attn_s)[t * 2 + 1] = make_float4(e[4], e[5], e[6], e[7]);
    }
    __syncthreads();

    // ---- phase B: U partials. thread -> (kk pair, d pair)
    {
        int dp = t & 63, kg = t >> 6;       // kg = wave id, kk0 = kg*2
        int d0 = dp * 2, kk0 = kg * 2;
        float4 ua = make_float4(0.f, 0.f, 0.f, 0.f);  // (kk0,d0)(kk0,d1)(kk1,d0)(kk1,d1)
        const uint* vp = (const uint*)(vbuf + ((size_t)b * NN + chunk * CHROWS) * ND + d0);
        for (int nn2 = 0; nn2 < CHROWS; ++nn2) {
            uint vr = vp[(size_t)nn2 * (ND / 2)];
            float v0 = bflo(vr), v1 = bfhi(vr);
            float2 a = *(const float2*)(attn_s + nn2 * NK + kk0);   // broadcast
            ua.x += a.x * v0; ua.y += a.x * v1;
            ua.z += a.y * v0; ua.w += a.y * v1;
        }
        size_t pb = ((size_t)chunk * NB + b) * (NK * ND);
        *(float2*)(pU + pb + (size_t)kk0 * ND + d0)       = make_float2(ua.x, ua.y);
        *(float2*)(pU + pb + (size_t)(kk0 + 1) * ND + d0) = make_float2(ua.z, ua.w);
    }
    __syncthreads();   // protect attn_s reads before tree-reduce overwrites

    // ---- phase C: S[kk] partial (tree reduce in LDS)
    float4* as4 = (float4*)attn_s;
    for (int s2 = CHROWS / 2; s2 >= 1; s2 >>= 1) {
        if (t < s2) {
            float4 a0 = as4[t * 2],     b0 = as4[(t + s2) * 2];
            float4 a1 = as4[t * 2 + 1], b1 = as4[(t + s2) * 2 + 1];
            a0.x += b0.x; a0.y += b0.y; a0.z += b0.z; a0.w += b0.w;
            a1.x += b1.x; a1.y += b1.y; a1.z += b1.z; a1.w += b1.w;
            as4[t * 2] = a0; as4[t * 2 + 1] = a1;
        }
        __syncthreads();
    }
    if (t < NK) pS[((size_t)chunk * NB + b) * NK + t] = attn_s[t];
}

// -------- reduce partials, normalize, GRU, LN, MLP residual, (+ next q)
// grid: 512 blocks (b*8+kk), 128 threads
__global__ __launch_bounds__(128) void finish_kernel(
    const float* __restrict__ pU, const float* __restrict__ pS,
    const float* __restrict__ slots_in, const float* __restrict__ wi,
    const float* __restrict__ wh, const float* __restrict__ bi,
    const float* __restrict__ bh, const float* __restrict__ lnw,
    const float* __restrict__ lnb, const float* __restrict__ w1,
    const float* __restrict__ b1, const float* __restrict__ w2,
    const float* __restrict__ b2, float* __restrict__ slots_out,
    const float* __restrict__ Wq, const float* __restrict__ lqw,
    const float* __restrict__ lqb, float* __restrict__ qout, int compute_q) {
    __shared__ float updL[ND], spL[ND], lnL[ND], hL[2 * ND], lnQ[ND];
    __shared__ float red[2], red2[2], redq[2], redq2[2];
    int bk = blockIdx.x;
    int b = bk >> 3, kk = bk & 7;
    int d = threadIdx.x;

    float U = 0.f, S = 0.f;
    for (int c = 0; c < NCHUNK; ++c) {
        U += pU[((size_t)c * NB + b) * (NK * ND) + kk * ND + d];
        S += pS[((size_t)c * NB + b) * NK + kk];
    }
    float upd = U / S;
    float spd = slots_in[(size_t)bk * ND + d];
    updL[d] = upd;
    spL[d] = spd;
    __syncthreads();

    // GRU gates (torch order r, z, n)
    float gxr = bi[d], gxz = bi[ND + d], gxn = bi[2 * ND + d];
    float ghr = bh[d], ghz = bh[ND + d], ghn = bh[2 * ND + d];
    for (int dd = 0; dd < ND; ++dd) {
        float u = updL[dd], s = spL[dd];
        const float* wip = wi + (size_t)dd * 3 * ND;
        const float* whp = wh + (size_t)dd * 3 * ND;
        gxr += u * wip[d];          ghr += s * whp[d];
        gxz += u * wip[ND + d];     ghz += s * whp[ND + d];
        gxn += u * wip[2 * ND + d]; ghn += s * whp[2 * ND + d];
    }
    float r_ = sigmoidf_(gxr + ghr);
    float z_ = sigmoidf_(gxz + ghz);
    float nn_ = tanhf(gxn + r_ * ghn);
    float snew = (1.f - z_) * nn_ + z_ * spd;

    // LayerNorm over D across 128 threads (2 waves)
    int wid = d >> 6;
    float sum = snew, sq = snew * snew;
#pragma unroll
    for (int m = 1; m < 64; m <<= 1) {
        sum += __shfl_xor(sum, m, 64);
        sq  += __shfl_xor(sq,  m, 64);
    }
    if ((d & 63) == 0) { red[wid] = sum; red2[wid] = sq; }
    __syncthreads();
    float tot = red[0] + red[1], totq = red2[0] + red2[1];
    float mu = tot * (1.f / ND);
    float var = totq * (1.f / ND) - mu * mu;
    float rs = rsqrtf(var + LN_EPS_C);
    lnL[d] = (snew - mu) * rs * lnw[d] + lnb[d];
    __syncthreads();

    // MLP: h = relu(ln @ w1 + b1), out = snew + h @ w2 + b2
    float h0 = b1[d], h1 = b1[ND + d];
    for (int dd = 0; dd < ND; ++dd) {
        float lv = lnL[dd];
        h0 += lv * w1[(size_t)dd * 2 * ND + d];
        h1 += lv * w1[(size_t)dd * 2 * ND + ND + d];
    }
    hL[d] = fmaxf(h0, 0.f);
    hL[ND + d] = fmaxf(h1, 0.f);
    __syncthreads();
    float od = snew + b2[d];
    for (int j = 0; j < 2 * ND; ++j) od += hL[j] * w2[(size_t)j * ND + d];
    slots_out[(size_t)bk * ND + d] = od;

    // ---- fused q for next iteration: q = LN(slots_new) @ Wq
    if (compute_q) {
        float s2 = od, q2 = od * od;
#pragma unroll
        for (int m = 1; m < 64; m <<= 1) {
            s2 += __shfl_xor(s2, m, 64);
            q2 += __shfl_xor(q2, m, 64);
        }
        if ((d & 63) == 0) { redq[wid] = s2; redq2[wid] = q2; }
        __syncthreads();
        float tq = redq[0] + redq[1], tqq = redq2[0] + redq2[1];
        float muq = tq * (1.f / ND);
        float vq = tqq * (1.f / ND) - muq * muq;
        float rsq = rsqrtf(vq + LN_EPS_C);
        lnQ[d] = (od - muq) * rsq * lqw[d] + lqb[d];
        __syncthreads();
        float qc = 0.f;
        for (int dd = 0; dd < ND; ++dd) qc += lnQ[dd] * Wq[(size_t)dd * ND + d];
        qout[(size_t)bk * ND + d] = qc;
    }
}

// ---------------------------------------------------------------------------
extern "C" void kernel_launch(void* const* d_in, const int* in_sizes, int n_in,
                              void* d_out, int out_size, void* d_ws, size_t ws_size,
                              hipStream_t stream) {
    const float* inp       = (const float*)d_in[0];
    const float* slot_init = (const float*)d_in[1];
    const float* Wq        = (const float*)d_in[2];
    const float* Wk        = (const float*)d_in[3];
    const float* Wv        = (const float*)d_in[4];
    const float* gru_wi    = (const float*)d_in[5];
    const float* gru_wh    = (const float*)d_in[6];
    const float* gru_bi    = (const float*)d_in[7];
    const float* gru_bh    = (const float*)d_in[8];
    const float* ln_in_w   = (const float*)d_in[9];
    const float* ln_in_b   = (const float*)d_in[10];
    const float* ln_sl_w   = (const float*)d_in[11];
    const float* ln_sl_b   = (const float*)d_in[12];
    const float* ln_ml_w   = (const float*)d_in[13];
    const float* ln_ml_b   = (const float*)d_in[14];
    const float* mlp_w1    = (const float*)d_in[15];
    const float* mlp_b1    = (const float*)d_in[16];
    const float* mlp_w2    = (const float*)d_in[17];
    const float* mlp_b2    = (const float*)d_in[18];

    char* wsb = (char*)d_ws;
    ushort* kb = (ushort*)wsb;                                  // 64 MB
    ushort* vb = kb + (size_t)NB * NN * ND;                     // 64 MB
    ushort* wt = vb + (size_t)NB * NN * ND;                     // 128 KB
    float* qb  = (float*)(wt + (size_t)NF * NF);
    float* sl  = qb + (size_t)NB * NK * ND;
    float* pU  = sl + (size_t)NB * NK * ND;
    float* pS  = pU + (size_t)NCHUNK * NB * NK * ND;

    init_slots_k<<<(NB * NK * ND) / 256, 256, 0, stream>>>(slot_init, sl);
    wconv_k<<<NF, NF, 0, stream>>>(Wk, Wv, wt);
    ln_project_mfma<<<(NB * NN) / MT, 256, 0, stream>>>(inp, wt, ln_in_w, ln_in_b, kb, vb);
    q_kernel<<<NB * NK, 64, 0, stream>>>(sl, Wq, ln_sl_w, ln_sl_b, qb);

    for (int it = 0; it < 3; ++it) {
        attn_kernel<<<dim3(NCHUNK, NB), 256, 0, stream>>>(kb, vb, qb, pU, pS);
        float* outp = (it == 2) ? (float*)d_out : sl;
        finish_kernel<<<NB * NK, 128, 0, stream>>>(pU, pS, sl, gru_wi, gru_wh,
                                                   gru_bi, gru_bh, ln_ml_w, ln_ml_b,
                                                   mlp_w1, mlp_b1, mlp_w2, mlp_b2, outp,
                                                   Wq, ln_sl_w, ln_sl_b, qb, (it < 2) ? 1 : 0);
    }
}

// Round 4
// 690.760 us; speedup vs baseline: 1.9196x; 1.0169x over previous
//
#include <hip/hip_runtime.h>
#include <math.h>

#define NB 64
#define NN 4096
#define NF 256
#define ND 128
#define NK 8
#define NCHUNK 16
#define CHROWS 256   // NN / NCHUNK
#define MT 64        // rows per block in ln_project_mfma

typedef unsigned int uint;
typedef unsigned short ushort;
typedef __attribute__((ext_vector_type(8))) short short8;
typedef __attribute__((ext_vector_type(4))) float floatx4;

constexpr float LN_EPS_C   = 1e-5f;
constexpr float EPS_ATTN_C = 1e-8f;
constexpr float INV_SCALE  = 0.08838834764831845f; // 1/sqrt(128)

__device__ __forceinline__ float sigmoidf_(float x) { return 1.f / (1.f + expf(-x)); }
__device__ __forceinline__ ushort f2bf(float x) {
    uint u = __float_as_uint(x);
    return (ushort)((u + 0x7FFFu + ((u >> 16) & 1u)) >> 16);
}
__device__ __forceinline__ float bflo(uint u) { return __uint_as_float(u << 16); }
__device__ __forceinline__ float bfhi(uint u) { return __uint_as_float(u & 0xFFFF0000u); }

// ---------------------------------------------------------------- slot init
__global__ void init_slots_k(const float* __restrict__ init, float* __restrict__ slots) {
    int i = blockIdx.x * 256 + threadIdx.x;      // 65536 total
    slots[i] = init[i & (NK * ND - 1)];
}

// ---- weight convert into fragment-contiguous layout:
// wt2 uint4 index = (c16*8 + ks)*64 + lane ; elems j=0..7:
//   col c = c16*16 + (lane&15), f = ks*32 + (lane>>4)*8 + j
// grid: 128 blocks x 64 threads
__global__ void wconv_k(const float* __restrict__ Wk, const float* __restrict__ Wv,
                        ushort* __restrict__ wt2) {
    int idx = blockIdx.x * 64 + threadIdx.x;    // 0..8191 (uint4 index)
    int c16 = idx >> 9, ks = (idx >> 6) & 7, lane = idx & 63;
    int c = c16 * 16 + (lane & 15);
    int f0 = ks * 32 + (lane >> 4) * 8;
    ushort tmp[8];
#pragma unroll
    for (int j = 0; j < 8; ++j) {
        int f = f0 + j;
        float v = (c < ND) ? Wk[(size_t)f * ND + c] : Wv[(size_t)f * ND + (c - ND)];
        tmp[j] = f2bf(v);
    }
    *(uint4*)(wt2 + (size_t)idx * 8) = *(uint4*)tmp;
}

// -------------------- fused LN(inputs) + [x@Wk, x@Wv] via bf16 MFMA
// k out: transposed bf16-pair planes kT2[b][d2][n]  (uint = bf16(2*d2),bf16(2*d2+1))
// v out: row-major bf16 [b][n][d]
// grid: (B*N)/MT = 4096 blocks, 256 threads (4 waves)
__global__ __launch_bounds__(256) void ln_project_mfma(
    const float* __restrict__ inp, const ushort* __restrict__ wt2,
    const float* __restrict__ lw, const float* __restrict__ lb,
    uint* __restrict__ kt2, ushort* __restrict__ vout) {
    __shared__ ushort As[MT][264];   // 33 KB; row stride 528 B
    int t = threadIdx.x;
    size_t rowbase = (size_t)blockIdx.x * MT;
    size_t bidx = rowbase >> 12;          // batch (NN=4096 rows per batch)
    size_t nbase = rowbase & (NN - 1);    // local token base within batch

    // ---- LN phase: 16 threads/row, 16 rows/pass, 4 passes; bf16 to LDS
    {
        int rloc = t >> 4, seg = t & 15;
        const float4* lw4 = (const float4*)lw;
        const float4* lb4 = (const float4*)lb;
#pragma unroll
        for (int p = 0; p < 4; ++p) {
            int r = p * 16 + rloc;
            const float4* rowp = (const float4*)(inp + (rowbase + r) * NF);
            float4 xv[4];
            float sum = 0.f, sq = 0.f;
#pragma unroll
            for (int i = 0; i < 4; ++i) {
                xv[i] = rowp[seg * 4 + i];
                sum += xv[i].x + xv[i].y + xv[i].z + xv[i].w;
                sq += xv[i].x * xv[i].x + xv[i].y * xv[i].y + xv[i].z * xv[i].z + xv[i].w * xv[i].w;
            }
#pragma unroll
            for (int m = 8; m >= 1; m >>= 1) {
                sum += __shfl_xor(sum, m, 64);
                sq  += __shfl_xor(sq,  m, 64);
            }
            float mu = sum * (1.f / NF);
            float var = sq * (1.f / NF) - mu * mu;
            float rs = rsqrtf(var + LN_EPS_C);
#pragma unroll
            for (int i = 0; i < 4; ++i) {
                float4 w = lw4[seg * 4 + i], bb = lb4[seg * 4 + i], x = xv[i];
                float o0 = (x.x - mu) * rs * w.x + bb.x;
                float o1 = (x.y - mu) * rs * w.y + bb.y;
                float o2 = (x.z - mu) * rs * w.z + bb.z;
                float o3 = (x.w - mu) * rs * w.w + bb.w;
                uint2 pk;
                pk.x = (uint)f2bf(o0) | ((uint)f2bf(o1) << 16);
                pk.y = (uint)f2bf(o2) | ((uint)f2bf(o3) << 16);
                *(uint2*)&As[r][seg * 16 + i * 4] = pk;
            }
        }
    }
    __syncthreads();

    // ---- MFMA phase: wave w covers output cols [w*64, w*64+64) of [k|v]
    int w = t >> 6, lane = t & 63;
    int frow = lane & 15, q = lane >> 4;
    floatx4 acc[4][4];
#pragma unroll
    for (int mt = 0; mt < 4; ++mt)
#pragma unroll
        for (int nt = 0; nt < 4; ++nt) acc[mt][nt] = (floatx4)0.f;

#pragma unroll
    for (int ks = 0; ks < 8; ++ks) {
        short8 a[4], b[4];
#pragma unroll
        for (int nt = 0; nt < 4; ++nt)
            b[nt] = *(const short8*)(wt2 + ((((size_t)(w * 4 + nt) * 8 + ks) * 64 + lane) * 8));
#pragma unroll
        for (int mt = 0; mt < 4; ++mt)
            a[mt] = *(const short8*)&As[mt * 16 + frow][ks * 32 + q * 8];
#pragma unroll
        for (int mt = 0; mt < 4; ++mt)
#pragma unroll
            for (int nt = 0; nt < 4; ++nt)
                acc[mt][nt] = __builtin_amdgcn_mfma_f32_16x16x32_bf16(a[mt], b[nt], acc[mt][nt], 0, 0, 0);
    }

    __syncthreads();   // all A-frag reads done before As is reused for v repack

    // C/D layout: col=lane&15 (frow), row=q*4+reg
    if (w < 2) {
        // ---- k epilogue: transpose to kT2[b][d2][n_local] via lane-pair exchange
        int cbase = w * 64;
#pragma unroll
        for (int mt = 0; mt < 4; ++mt)
#pragma unroll
            for (int nt = 0; nt < 4; ++nt) {
                int c = cbase + nt * 16 + frow;
                uint u01 = (uint)f2bf(acc[mt][nt][0]) | ((uint)f2bf(acc[mt][nt][1]) << 16);
                uint u23 = (uint)f2bf(acc[mt][nt][2]) | ((uint)f2bf(acc[mt][nt][3]) << 16);
                uint p01 = __shfl_xor(u01, 1, 64);
                uint p23 = __shfl_xor(u23, 1, 64);
                if ((frow & 1) == 0) {
                    uint4 out;
                    out.x = (u01 & 0xFFFFu) | (p01 << 16);
                    out.y = (u01 >> 16) | (p01 & 0xFFFF0000u);
                    out.z = (u23 & 0xFFFFu) | (p23 << 16);
                    out.w = (u23 >> 16) | (p23 & 0xFFFF0000u);
                    size_t nloc = nbase + mt * 16 + q * 4;
                    *(uint4*)(kt2 + (bidx * 64 + (size_t)(c >> 1)) * NN + nloc) = out;
                }
            }
    } else {
        // ---- v epilogue: park in As (bf16), repack below
        int cbase = (w & 1) * 64;
#pragma unroll
        for (int mt = 0; mt < 4; ++mt)
#pragma unroll
            for (int nt = 0; nt < 4; ++nt) {
                int c = cbase + nt * 16 + frow;
#pragma unroll
                for (int i = 0; i < 4; ++i)
                    As[mt * 16 + q * 4 + i][c] = f2bf(acc[mt][nt][i]);
            }
    }
    __syncthreads();

    // ---- v repack: all 256 threads, coalesced uint4 stores
    {
        int r = t >> 2, part = t & 3;
#pragma unroll
        for (int u = 0; u < 4; ++u) {
            uint4 val = *(const uint4*)&As[r][part * 32 + u * 8];
            *(uint4*)(vout + (rowbase + r) * ND + part * 32 + u * 8) = val;
        }
    }
}

// ------------------------------------------------- q = LN(slots) @ Wq (iter 0)
__global__ __launch_bounds__(64) void q_kernel(
    const float* __restrict__ slots, const float* __restrict__ Wq,
    const float* __restrict__ lw, const float* __restrict__ lb,
    float* __restrict__ qout) {
    __shared__ float sln[ND];
    int bk = blockIdx.x;
    int t = threadIdx.x;
    const float* sp = slots + (size_t)bk * ND;
    float s0 = sp[t], s1 = sp[t + 64];
    float sum = s0 + s1, sq = s0 * s0 + s1 * s1;
#pragma unroll
    for (int m = 1; m < 64; m <<= 1) {
        sum += __shfl_xor(sum, m, 64);
        sq  += __shfl_xor(sq,  m, 64);
    }
    float mu = sum * (1.f / ND);
    float var = sq * (1.f / ND) - mu * mu;
    float rs = rsqrtf(var + LN_EPS_C);
    sln[t]      = (s0 - mu) * rs * lw[t]      + lb[t];
    sln[t + 64] = (s1 - mu) * rs * lw[t + 64] + lb[t + 64];
    __syncthreads();
    float q0 = 0.f, q1 = 0.f;
    for (int dd = 0; dd < ND; ++dd) {
        float v = sln[dd];
        q0 += v * Wq[dd * ND + t];
        q1 += v * Wq[dd * ND + 64 + t];
    }
    qout[(size_t)bk * ND + t] = q0;
    qout[(size_t)bk * ND + 64 + t] = q1;
}

// ------------- attention pass: logits -> softmax(K) -> partial U, S per chunk
// k is transposed bf16-pair planes; v row-major bf16.
// grid: (NCHUNK, NB), 256 threads
__global__ __launch_bounds__(256) void attn_kernel(
    const uint* __restrict__ kt2, const ushort* __restrict__ vbuf,
    const float* __restrict__ qbuf, float* __restrict__ pU,
    float* __restrict__ pS) {
    __shared__ __align__(16) float attn_s[CHROWS * NK];   // 8 KB
    __shared__ __align__(16) float qs2[64 * 16];          // 4 KB: [d2][kk][2]
    int t = threadIdx.x;
    int chunk = blockIdx.x, b = blockIdx.y;
    int n = chunk * CHROWS + t;

    // build qs2[d2*16 + kk*2 + (d&1)] = q[kk][d]
#pragma unroll
    for (int p = 0; p < 4; ++p) {
        int idx = p * 256 + t;
        int kk = idx >> 7, d = idx & 127;
        qs2[(d >> 1) * 16 + kk * 2 + (d & 1)] = qbuf[(size_t)b * NK * ND + idx];
    }
    __syncthreads();

    // ---- phase A: logits + softmax over K (thread = token, coalesced k loads)
    {
        const uint* ktp = kt2 + (size_t)b * 64 * NN + n;
        float lg[NK];
#pragma unroll
        for (int kk = 0; kk < NK; ++kk) lg[kk] = 0.f;
#pragma unroll 8
        for (int j = 0; j < 64; ++j) {
            uint kr = ktp[(size_t)j * NN];
            float k0 = bflo(kr), k1 = bfhi(kr);
            const float4* qp = (const float4*)(qs2 + j * 16);
#pragma unroll
            for (int c = 0; c < 4; ++c) {
                float4 qq = qp[c];
                lg[2 * c]     += k0 * qq.x + k1 * qq.y;
                lg[2 * c + 1] += k0 * qq.z + k1 * qq.w;
            }
        }
        float mx = -1e30f;
#pragma unroll
        for (int kk = 0; kk < NK; ++kk) { lg[kk] *= INV_SCALE; mx = fmaxf(mx, lg[kk]); }
        float se = 0.f;
        float e[NK];
#pragma unroll
        for (int kk = 0; kk < NK; ++kk) { e[kk] = expf(lg[kk] - mx); se += e[kk]; }
        float inv = 1.f / se;
#pragma unroll
        for (int kk = 0; kk < NK; ++kk) e[kk] = e[kk] * inv + EPS_ATTN_C;
        ((float4*)attn_s)[t * 2]     = make_float4(e[0], e[1], e[2], e[3]);
        ((float4*)attn_s)[t * 2 + 1] = make_float4(e[4], e[5], e[6], e[7]);
    }
    __syncthreads();

    // ---- phase B: U partials. wave kg -> kk pair, lane -> d pair
    {
        int dp = t & 63, kg = t >> 6;
        int d0 = dp * 2, kk0 = kg * 2;
        float4 ua = make_float4(0.f, 0.f, 0.f, 0.f);
        const uint* vp = (const uint*)(vbuf + ((size_t)b * NN + chunk * CHROWS) * ND + d0);
        for (int nn2 = 0; nn2 < CHROWS; ++nn2) {
            uint vr = vp[(size_t)nn2 * (ND / 2)];
            float v0 = bflo(vr), v1 = bfhi(vr);
            float2 a = *(const float2*)(attn_s + nn2 * NK + kk0);
            ua.x += a.x * v0; ua.y += a.x * v1;
            ua.z += a.y * v0; ua.w += a.y * v1;
        }
        size_t pb = ((size_t)chunk * NB + b) * (NK * ND);
        *(float2*)(pU + pb + (size_t)kk0 * ND + d0)       = make_float2(ua.x, ua.y);
        *(float2*)(pU + pb + (size_t)(kk0 + 1) * ND + d0) = make_float2(ua.z, ua.w);
    }
    __syncthreads();

    // ---- phase C: S[kk] partial (tree reduce in LDS)
    float4* as4 = (float4*)attn_s;
    for (int s2 = CHROWS / 2; s2 >= 1; s2 >>= 1) {
        if (t < s2) {
            float4 a0 = as4[t * 2],     b0 = as4[(t + s2) * 2];
            float4 a1 = as4[t * 2 + 1], b1 = as4[(t + s2) * 2 + 1];
            a0.x += b0.x; a0.y += b0.y; a0.z += b0.z; a0.w += b0.w;
            a1.x += b1.x; a1.y += b1.y; a1.z += b1.z; a1.w += b1.w;
            as4[t * 2] = a0; as4[t * 2 + 1] = a1;
        }
        __syncthreads();
    }
    if (t < NK) pS[((size_t)chunk * NB + b) * NK + t] = attn_s[t];
}

// -------- reduce partials, normalize, GRU, LN, MLP residual, (+ next q)
__global__ __launch_bounds__(128) void finish_kernel(
    const float* __restrict__ pU, const float* __restrict__ pS,
    const float* __restrict__ slots_in, const float* __restrict__ wi,
    const float* __restrict__ wh, const float* __restrict__ bi,
    const float* __restrict__ bh, const float* __restrict__ lnw,
    const float* __restrict__ lnb, const float* __restrict__ w1,
    const float* __restrict__ b1, const float* __restrict__ w2,
    const float* __restrict__ b2, float* __restrict__ slots_out,
    const float* __restrict__ Wq, const float* __restrict__ lqw,
    const float* __restrict__ lqb, float* __restrict__ qout, int compute_q) {
    __shared__ float updL[ND], spL[ND], lnL[ND], hL[2 * ND], lnQ[ND];
    __shared__ float red[2], red2[2], redq[2], redq2[2];
    int bk = blockIdx.x;
    int b = bk >> 3, kk = bk & 7;
    int d = threadIdx.x;

    float U = 0.f, S = 0.f;
    for (int c = 0; c < NCHUNK; ++c) {
        U += pU[((size_t)c * NB + b) * (NK * ND) + kk * ND + d];
        S += pS[((size_t)c * NB + b) * NK + kk];
    }
    float upd = U / S;
    float spd = slots_in[(size_t)bk * ND + d];
    updL[d] = upd;
    spL[d] = spd;
    __syncthreads();

    float gxr = bi[d], gxz = bi[ND + d], gxn = bi[2 * ND + d];
    float ghr = bh[d], ghz = bh[ND + d], ghn = bh[2 * ND + d];
    for (int dd = 0; dd < ND; ++dd) {
        float u = updL[dd], s = spL[dd];
        const float* wip = wi + (size_t)dd * 3 * ND;
        const float* whp = wh + (size_t)dd * 3 * ND;
        gxr += u * wip[d];          ghr += s * whp[d];
        gxz += u * wip[ND + d];     ghz += s * whp[ND + d];
        gxn += u * wip[2 * ND + d]; ghn += s * whp[2 * ND + d];
    }
    float r_ = sigmoidf_(gxr + ghr);
    float z_ = sigmoidf_(gxz + ghz);
    float nn_ = tanhf(gxn + r_ * ghn);
    float snew = (1.f - z_) * nn_ + z_ * spd;

    int wid = d >> 6;
    float sum = snew, sq = snew * snew;
#pragma unroll
    for (int m = 1; m < 64; m <<= 1) {
        sum += __shfl_xor(sum, m, 64);
        sq  += __shfl_xor(sq,  m, 64);
    }
    if ((d & 63) == 0) { red[wid] = sum; red2[wid] = sq; }
    __syncthreads();
    float tot = red[0] + red[1], totq = red2[0] + red2[1];
    float mu = tot * (1.f / ND);
    float var = totq * (1.f / ND) - mu * mu;
    float rs = rsqrtf(var + LN_EPS_C);
    lnL[d] = (snew - mu) * rs * lnw[d] + lnb[d];
    __syncthreads();

    float h0 = b1[d], h1 = b1[ND + d];
    for (int dd = 0; dd < ND; ++dd) {
        float lv = lnL[dd];
        h0 += lv * w1[(size_t)dd * 2 * ND + d];
        h1 += lv * w1[(size_t)dd * 2 * ND + ND + d];
    }
    hL[d] = fmaxf(h0, 0.f);
    hL[ND + d] = fmaxf(h1, 0.f);
    __syncthreads();
    float od = snew + b2[d];
    for (int j = 0; j < 2 * ND; ++j) od += hL[j] * w2[(size_t)j * ND + d];
    slots_out[(size_t)bk * ND + d] = od;

    if (compute_q) {
        float s2 = od, q2 = od * od;
#pragma unroll
        for (int m = 1; m < 64; m <<= 1) {
            s2 += __shfl_xor(s2, m, 64);
            q2 += __shfl_xor(q2, m, 64);
        }
        if ((d & 63) == 0) { redq[wid] = s2; redq2[wid] = q2; }
        __syncthreads();
        float tq = redq[0] + redq[1], tqq = redq2[0] + redq2[1];
        float muq = tq * (1.f / ND);
        float vq = tqq * (1.f / ND) - muq * muq;
        float rsq = rsqrtf(vq + LN_EPS_C);
        lnQ[d] = (od - muq) * rsq * lqw[d] + lqb[d];
        __syncthreads();
        float qc = 0.f;
        for (int dd = 0; dd < ND; ++dd) qc += lnQ[dd] * Wq[(size_t)dd * ND + d];
        qout[(size_t)bk * ND + d] = qc;
    }
}

// ---------------------------------------------------------------------------
extern "C" void kernel_launch(void* const* d_in, const int* in_sizes, int n_in,
                              void* d_out, int out_size, void* d_ws, size_t ws_size,
                              hipStream_t stream) {
    const float* inp       = (const float*)d_in[0];
    const float* slot_init = (const float*)d_in[1];
    const float* Wq        = (const float*)d_in[2];
    const float* Wk        = (const float*)d_in[3];
    const float* Wv        = (const float*)d_in[4];
    const float* gru_wi    = (const float*)d_in[5];
    const float* gru_wh    = (const float*)d_in[6];
    const float* gru_bi    = (const float*)d_in[7];
    const float* gru_bh    = (const float*)d_in[8];
    const float* ln_in_w   = (const float*)d_in[9];
    const float* ln_in_b   = (const float*)d_in[10];
    const float* ln_sl_w   = (const float*)d_in[11];
    const float* ln_sl_b   = (const float*)d_in[12];
    const float* ln_ml_w   = (const float*)d_in[13];
    const float* ln_ml_b   = (const float*)d_in[14];
    const float* mlp_w1    = (const float*)d_in[15];
    const float* mlp_b1    = (const float*)d_in[16];
    const float* mlp_w2    = (const float*)d_in[17];
    const float* mlp_b2    = (const float*)d_in[18];

    char* wsb = (char*)d_ws;
    uint* kt2   = (uint*)wsb;                                   // 64 MB
    ushort* vb  = (ushort*)(wsb + (size_t)NB * 64 * NN * 4);    // 64 MB
    ushort* wt2 = vb + (size_t)NB * NN * ND;                    // 128 KB
    float* qb   = (float*)(wt2 + (size_t)NF * NF);
    float* sl   = qb + (size_t)NB * NK * ND;
    float* pU   = sl + (size_t)NB * NK * ND;
    float* pS   = pU + (size_t)NCHUNK * NB * NK * ND;

    init_slots_k<<<(NB * NK * ND) / 256, 256, 0, stream>>>(slot_init, sl);
    wconv_k<<<128, 64, 0, stream>>>(Wk, Wv, wt2);
    ln_project_mfma<<<(NB * NN) / MT, 256, 0, stream>>>(inp, wt2, ln_in_w, ln_in_b, kt2, vb);
    q_kernel<<<NB * NK, 64, 0, stream>>>(sl, Wq, ln_sl_w, ln_sl_b, qb);

    for (int it = 0; it < 3; ++it) {
        attn_kernel<<<dim3(NCHUNK, NB), 256, 0, stream>>>(kt2, vb, qb, pU, pS);
        float* outp = (it == 2) ? (float*)d_out : sl;
        finish_kernel<<<NB * NK, 128, 0, stream>>>(pU, pS, sl, gru_wi, gru_wh,
                                                   gru_bi, gru_bh, ln_ml_w, ln_ml_b,
                                                   mlp_w1, mlp_b1, mlp_w2, mlp_b2, outp,
                                                   Wq, ln_sl_w, ln_sl_b, qb, (it < 2) ? 1 : 0);
    }
}